// Round 2
// baseline (6916.840 us; speedup 1.0000x reference)
//
#include <hip/hip_runtime.h>

// LSTM: B=64, T=512, D=512, H=1024, G=4H=4096
// d_out: output[64][512][1024] fp32, then h_last[64][1024], c_last[64][1024]

typedef __attribute__((ext_vector_type(4))) float f32x4;
typedef __attribute__((ext_vector_type(8))) __bf16 bf16x8;
typedef __attribute__((ext_vector_type(4))) __bf16 bf16x4;

__device__ __forceinline__ f32x4 mfma16(bf16x8 a, bf16x8 b, f32x4 c) {
  return __builtin_amdgcn_mfma_f32_16x16x32_bf16(a, b, c, 0, 0, 0);
}
__device__ __forceinline__ float sigm(float x) {
  return __builtin_amdgcn_rcpf(1.0f + __expf(-x));
}
__device__ __forceinline__ float tanh_(float x) {
  return 2.0f * __builtin_amdgcn_rcpf(1.0f + __expf(-2.0f * x)) - 1.0f;
}

// ---------- Phase 1: gates[t][g][b] = sum_d W_ih[g,d]*x[b,t,d] + b_ih[g] + b_hh[g]
// GEMM M=4096(g), N=32768(n=t*64+b), K=512. Tile 128x128, BK=32, 4 waves (2x2).
template<bool GF32>
__global__ __launch_bounds__(256) void k_gates(
    const float* __restrict__ x, const float* __restrict__ Wih,
    const float* __restrict__ bih, const float* __restrict__ bhh,
    void* __restrict__ gates)
{
  __shared__ __align__(16) __bf16 lA[128][40];  // [g][k] padded
  __shared__ __align__(16) __bf16 lB[128][40];  // [n][k] padded
  int bid = blockIdx.x;
  int grp = bid >> 9;
  int rem = bid & 511;
  int mt = rem & 31;
  int nt = (grp << 4) + (rem >> 5);
  const int m0 = mt << 7, n0 = nt << 7;
  const int tid = threadIdx.x, lane = tid & 63, wave = tid >> 6;
  const int cl = lane & 15, rg = lane >> 4;
  const int wm = (wave >> 1) << 6, wn = (wave & 1) << 6;
  f32x4 acc[4][4] = {};

  const int r = tid >> 1;
  const int kh = (tid & 1) << 4;
  const float* aSrc = Wih + (size_t)(m0 + r) * 512 + kh;
  const int nn = n0 + r;
  const float* bSrc = x + ((size_t)(nn & 63) * 512 + (nn >> 6)) * 512 + kh;

  for (int k0 = 0; k0 < 512; k0 += 32) {
    __syncthreads();
    #pragma unroll
    for (int i = 0; i < 16; i += 4) {
      f32x4 va = *(const f32x4*)(aSrc + k0 + i);
      f32x4 vb = *(const f32x4*)(bSrc + k0 + i);
      bf16x4 pa, pb;
      #pragma unroll
      for (int j = 0; j < 4; ++j) { pa[j] = (__bf16)va[j]; pb[j] = (__bf16)vb[j]; }
      *(bf16x4*)&lA[r][kh + i] = pa;
      *(bf16x4*)&lB[r][kh + i] = pb;
    }
    __syncthreads();
    bf16x8 afr[4], bfr[4];
    #pragma unroll
    for (int q = 0; q < 4; ++q) {
      afr[q] = *(const bf16x8*)&lA[wm + q * 16 + cl][rg * 8];
      bfr[q] = *(const bf16x8*)&lB[wn + q * 16 + cl][rg * 8];
    }
    #pragma unroll
    for (int mi = 0; mi < 4; ++mi)
      #pragma unroll
      for (int ni = 0; ni < 4; ++ni)
        acc[mi][ni] = mfma16(afr[mi], bfr[ni], acc[mi][ni]);
  }

  #pragma unroll
  for (int mi = 0; mi < 4; ++mi) {
    int gb = m0 + wm + mi * 16 + rg * 4;
    f32x4 bsum = *(const f32x4*)(bih + gb);
    bsum += *(const f32x4*)(bhh + gb);
    #pragma unroll
    for (int ni = 0; ni < 4; ++ni) {
      int n = n0 + wn + ni * 16 + cl;
      int tt = n >> 6, bb = n & 63;
      #pragma unroll
      for (int v = 0; v < 4; ++v) {
        float val = acc[mi][ni][v] + bsum[v];
        size_t idx = ((size_t)tt * 4096 + (size_t)(gb + v)) * 64 + bb;
        if (GF32) ((float*)gates)[idx] = val;
        else      ((__bf16*)gates)[idx] = (__bf16)val;
      }
    }
  }
}

// ---------- grid barrier: 8 split counters (128B apart), relaxed polls,
// explicit agent fences once per barrier (no per-poll L2 invalidate).
__device__ __forceinline__ void gridbar(unsigned* bars, unsigned target, int bid) {
  __syncthreads();
  if (threadIdx.x == 0) {
    __builtin_amdgcn_fence(__ATOMIC_RELEASE, "agent");
    __hip_atomic_fetch_add(&bars[(bid & 7) * 32], 1u, __ATOMIC_RELAXED,
                           __HIP_MEMORY_SCOPE_AGENT);
    for (;;) {
      unsigned s = 0;
      #pragma unroll
      for (int i = 0; i < 8; ++i)
        s += __hip_atomic_load(&bars[i * 32], __ATOMIC_RELAXED,
                               __HIP_MEMORY_SCOPE_AGENT);
      if (s >= target) break;
      __builtin_amdgcn_s_sleep(1);
    }
    __builtin_amdgcn_fence(__ATOMIC_ACQUIRE, "agent");
  }
  __syncthreads();
}

// ---------- Phase 2: persistent recurrence. 128 blocks x 256 thr (4 waves).
template<bool GF32>
__global__ __launch_bounds__(256, 1) void k_rnn(
    const void* __restrict__ gates, const float* __restrict__ Whh,
    __bf16* __restrict__ hA, __bf16* __restrict__ hB,
    unsigned* __restrict__ bars,
    float* __restrict__ out, float* __restrict__ hlast, float* __restrict__ clast)
{
  const int tid = threadIdx.x, lane = tid & 63, wave = tid >> 6;
  const int cl = lane & 15, rg = lane >> 4;
  const int hb = blockIdx.x << 3;   // 8 hidden units
  const int bo = wave << 4;         // batch offset
  const int bb = bo + rg * 4;       // base batch for acc rows

  // load W_hh fragments once (held in registers for all 512 steps)
  bf16x8 wf[2][32];
  int wrowA[2];
  #pragma unroll
  for (int nt = 0; nt < 2; ++nt) {
    int nl = nt * 16 + cl;
    int wrow = (nl >> 3) * 1024 + hb + (nl & 7);
    wrowA[nt] = wrow;
    const float* wsrc = Whh + (size_t)wrow * 1024 + rg * 8;
    #pragma unroll
    for (int kt = 0; kt < 32; ++kt) {
      f32x4 lo = *(const f32x4*)(wsrc + kt * 32);
      f32x4 hi = *(const f32x4*)(wsrc + kt * 32 + 4);
      bf16x8 f;
      #pragma unroll
      for (int j = 0; j < 4; ++j) { f[j] = (__bf16)lo[j]; f[4 + j] = (__bf16)hi[j]; }
      wf[nt][kt] = f;
    }
  }

  float cst[4] = {0.f, 0.f, 0.f, 0.f};

  f32x4 gp[2];
  #pragma unroll
  for (int nt = 0; nt < 2; ++nt) {
    size_t idx = (size_t)wrowA[nt] * 64 + bb;
    if (GF32) gp[nt] = *(const f32x4*)((const float*)gates + idx);
    else {
      bf16x4 q = *(const bf16x4*)((const __bf16*)gates + idx);
      #pragma unroll
      for (int j = 0; j < 4; ++j) gp[nt][j] = (float)q[j];
    }
  }

  for (int t = 0; t < 512; ++t) {
    const __bf16* hprev = (t & 1) ? hB : hA;
    __bf16* hnext = (t & 1) ? hA : hB;

    f32x4 acc0 = gp[0], acc1 = gp[1];

    if (t < 511) {
      #pragma unroll
      for (int nt = 0; nt < 2; ++nt) {
        size_t idx = ((size_t)(t + 1) * 4096 + (size_t)wrowA[nt]) * 64 + bb;
        if (GF32) gp[nt] = *(const f32x4*)((const float*)gates + idx);
        else {
          bf16x4 q = *(const bf16x4*)((const __bf16*)gates + idx);
          #pragma unroll
          for (int j = 0; j < 4; ++j) gp[nt][j] = (float)q[j];
        }
      }
    }

    const __bf16* hrow = hprev + (size_t)(bo + cl) * 1024 + rg * 8;
    #pragma unroll
    for (int half = 0; half < 2; ++half) {
      bf16x8 af[16];
      #pragma unroll
      for (int kt = 0; kt < 16; ++kt)
        af[kt] = *(const bf16x8*)(hrow + (size_t)(half * 16 + kt) * 32);
      #pragma unroll
      for (int kt = 0; kt < 16; ++kt) {
        acc0 = mfma16(af[kt], wf[0][half * 16 + kt], acc0);
        acc1 = mfma16(af[kt], wf[1][half * 16 + kt], acc1);
      }
    }

    f32x4 a0s, a1s;
    #pragma unroll
    for (int j = 0; j < 4; ++j) {
      a0s[j] = __shfl_xor(acc0[j], 8, 64);
      a1s[j] = __shfl_xor(acc1[j], 8, 64);
    }
    if (cl < 8) {
      #pragma unroll
      for (int v = 0; v < 4; ++v) {
        float iv = sigm(acc0[v]);
        float fv = sigm(a0s[v]);
        float gv = tanh_(acc1[v]);
        float ov = sigm(a1s[v]);
        float c = fv * cst[v] + iv * gv;
        cst[v] = c;
        float hv = ov * tanh_(c);
        int b = bb + v;
        hnext[(size_t)b * 1024 + hb + cl] = (__bf16)hv;
        __builtin_nontemporal_store(hv, &out[((size_t)b * 512 + t) * 1024 + hb + cl]);
        if (t == 511) {
          __builtin_nontemporal_store(hv, &hlast[(size_t)b * 1024 + hb + cl]);
          __builtin_nontemporal_store(c,  &clast[(size_t)b * 1024 + hb + cl]);
        }
      }
    }
    if (t < 511) gridbar(bars, (unsigned)(t + 1) * gridDim.x, blockIdx.x);
  }
}

extern "C" void kernel_launch(void* const* d_in, const int* in_sizes, int n_in,
                              void* d_out, int out_size, void* d_ws, size_t ws_size,
                              hipStream_t stream) {
  const float* x   = (const float*)d_in[0];
  const float* Wih = (const float*)d_in[1];
  const float* bih = (const float*)d_in[2];
  const float* Whh = (const float*)d_in[3];
  const float* bhh = (const float*)d_in[4];
  float* out   = (float*)d_out;
  float* hlast = out + (size_t)64 * 512 * 1024;
  float* clast = hlast + (size_t)64 * 1024;

  char* ws = (char*)d_ws;
  unsigned* bars = (unsigned*)ws;                 // 8 counters, 128B apart
  __bf16* hA = (__bf16*)(ws + 4096);
  __bf16* hB = (__bf16*)(ws + 4096 + 131072);
  void* gates = (void*)(ws + (1 << 20));
  const size_t need_f32 = (size_t)(1 << 20) + (size_t)512 * 4096 * 64 * 4;
  bool gf32 = (ws_size >= need_f32);

  hipMemsetAsync(bars, 0, 1024, stream);
  hipMemsetAsync(hA, 0, 131072, stream);

  if (gf32) {
    k_gates<true><<<8192, 256, 0, stream>>>(x, Wih, bih, bhh, gates);
    k_rnn<true><<<128, 256, 0, stream>>>(gates, Whh, hA, hB, bars, out, hlast, clast);
  } else {
    k_gates<false><<<8192, 256, 0, stream>>>(x, Wih, bih, bhh, gates);
    k_rnn<false><<<128, 256, 0, stream>>>(gates, Whh, hA, hB, bars, out, hlast, clast);
  }
}

// Round 3
// 5516.270 us; speedup vs baseline: 1.2539x; 1.2539x over previous
//
#include <hip/hip_runtime.h>

// LSTM: B=64, T=512, D=512, H=1024, G=4H=4096
// d_out: output[64][512][1024] fp32, then h_last[64][1024], c_last[64][1024]

typedef __attribute__((ext_vector_type(4))) float f32x4;
typedef __attribute__((ext_vector_type(8))) __bf16 bf16x8;
typedef __attribute__((ext_vector_type(4))) __bf16 bf16x4;

__device__ __forceinline__ f32x4 mfma16(bf16x8 a, bf16x8 b, f32x4 c) {
  return __builtin_amdgcn_mfma_f32_16x16x32_bf16(a, b, c, 0, 0, 0);
}
__device__ __forceinline__ float sigm(float x) {
  return __builtin_amdgcn_rcpf(1.0f + __expf(-x));
}
__device__ __forceinline__ float tanh_(float x) {
  return 2.0f * __builtin_amdgcn_rcpf(1.0f + __expf(-2.0f * x)) - 1.0f;
}

// ---------- Phase 1: gates[t][g][b] = sum_d W_ih[g,d]*x[b,t,d] + b_ih[g] + b_hh[g]
// (unchanged from R1/R2 — ~370us; optimize later if it becomes dominant)
template<bool GF32>
__global__ __launch_bounds__(256) void k_gates(
    const float* __restrict__ x, const float* __restrict__ Wih,
    const float* __restrict__ bih, const float* __restrict__ bhh,
    void* __restrict__ gates)
{
  __shared__ __align__(16) __bf16 lA[128][40];
  __shared__ __align__(16) __bf16 lB[128][40];
  int bid = blockIdx.x;
  int grp = bid >> 9;
  int rem = bid & 511;
  int mt = rem & 31;
  int nt = (grp << 4) + (rem >> 5);
  const int m0 = mt << 7, n0 = nt << 7;
  const int tid = threadIdx.x, lane = tid & 63, wave = tid >> 6;
  const int cl = lane & 15, rg = lane >> 4;
  const int wm = (wave >> 1) << 6, wn = (wave & 1) << 6;
  f32x4 acc[4][4] = {};

  const int r = tid >> 1;
  const int kh = (tid & 1) << 4;
  const float* aSrc = Wih + (size_t)(m0 + r) * 512 + kh;
  const int nn = n0 + r;
  const float* bSrc = x + ((size_t)(nn & 63) * 512 + (nn >> 6)) * 512 + kh;

  for (int k0 = 0; k0 < 512; k0 += 32) {
    __syncthreads();
    #pragma unroll
    for (int i = 0; i < 16; i += 4) {
      f32x4 va = *(const f32x4*)(aSrc + k0 + i);
      f32x4 vb = *(const f32x4*)(bSrc + k0 + i);
      bf16x4 pa, pb;
      #pragma unroll
      for (int j = 0; j < 4; ++j) { pa[j] = (__bf16)va[j]; pb[j] = (__bf16)vb[j]; }
      *(bf16x4*)&lA[r][kh + i] = pa;
      *(bf16x4*)&lB[r][kh + i] = pb;
    }
    __syncthreads();
    bf16x8 afr[4], bfr[4];
    #pragma unroll
    for (int q = 0; q < 4; ++q) {
      afr[q] = *(const bf16x8*)&lA[wm + q * 16 + cl][rg * 8];
      bfr[q] = *(const bf16x8*)&lB[wn + q * 16 + cl][rg * 8];
    }
    #pragma unroll
    for (int mi = 0; mi < 4; ++mi)
      #pragma unroll
      for (int ni = 0; ni < 4; ++ni)
        acc[mi][ni] = mfma16(afr[mi], bfr[ni], acc[mi][ni]);
  }

  #pragma unroll
  for (int mi = 0; mi < 4; ++mi) {
    int gb = m0 + wm + mi * 16 + rg * 4;
    f32x4 bsum = *(const f32x4*)(bih + gb);
    bsum += *(const f32x4*)(bhh + gb);
    #pragma unroll
    for (int ni = 0; ni < 4; ++ni) {
      int n = n0 + wn + ni * 16 + cl;
      int tt = n >> 6, bb = n & 63;
      #pragma unroll
      for (int v = 0; v < 4; ++v) {
        float val = acc[mi][ni][v] + bsum[v];
        size_t idx = ((size_t)tt * 4096 + (size_t)(gb + v)) * 64 + bb;
        if (GF32) ((float*)gates)[idx] = val;
        else      ((__bf16*)gates)[idx] = (__bf16)val;
      }
    }
  }
}

// ---------- grid barrier: NO fences, no cache maintenance. All shared data
// moves via system-scope (sc0 sc1, LLC-coherent) instructions; __syncthreads
// drains vmcnt(0) so h stores are at LLC before the arrival add.
__device__ __forceinline__ void gridbar(unsigned* bars, unsigned target, int bid) {
  __syncthreads();
  if (threadIdx.x < 8) {
    if (threadIdx.x == 0)
      __hip_atomic_fetch_add(&bars[(bid & 7) * 32], 1u, __ATOMIC_RELAXED,
                             __HIP_MEMORY_SCOPE_SYSTEM);
    for (;;) {
      unsigned v = __hip_atomic_load(&bars[threadIdx.x * 32], __ATOMIC_RELAXED,
                                     __HIP_MEMORY_SCOPE_SYSTEM);
      v += __shfl_xor((int)v, 1, 64);
      v += __shfl_xor((int)v, 2, 64);
      v += __shfl_xor((int)v, 4, 64);
      if (v >= target) break;
      __builtin_amdgcn_s_sleep(1);
    }
  }
  __syncthreads();
}

// ---------- Phase 2: persistent recurrence. 128 blocks x 256 thr (4 waves).
// W_hh slice (32 gate rows, bf16) lives in LDS (64KB) as pre-built MFMA
// B-fragments. h exchange via system-scope relaxed atomics (LLC-coherent).
template<bool GF32>
__global__ __launch_bounds__(256, 1) void k_rnn(
    const void* __restrict__ gates, const float* __restrict__ Whh,
    __bf16* __restrict__ hA, __bf16* __restrict__ hB,
    unsigned* __restrict__ bars,
    float* __restrict__ out, float* __restrict__ hlast, float* __restrict__ clast)
{
  __shared__ __align__(16) __bf16 WF[2 * 32 * 64 * 8];  // 64 KB
  const int tid = threadIdx.x, lane = tid & 63, wave = tid >> 6;
  const int cl = lane & 15, rg = lane >> 4;
  const int hb = blockIdx.x << 3;   // 8 hidden units
  const int bo = wave << 4;         // batch offset
  const int bb = bo + rg * 4;       // base batch for acc rows

  // gate-row indices (per lane; identical across waves)
  int wrowA[2];
  #pragma unroll
  for (int nt = 0; nt < 2; ++nt) {
    int nl = nt * 16 + cl;
    wrowA[nt] = (nl >> 3) * 1024 + hb + (nl & 7);
  }

  // wave 0 builds the W_hh B-fragments into LDS (identical across waves)
  if (wave == 0) {
    #pragma unroll
    for (int nt = 0; nt < 2; ++nt) {
      const float* wsrc = Whh + (size_t)wrowA[nt] * 1024 + rg * 8;
      for (int kt = 0; kt < 32; ++kt) {
        f32x4 lo = *(const f32x4*)(wsrc + kt * 32);
        f32x4 hi = *(const f32x4*)(wsrc + kt * 32 + 4);
        bf16x8 f;
        #pragma unroll
        for (int j = 0; j < 4; ++j) { f[j] = (__bf16)lo[j]; f[4 + j] = (__bf16)hi[j]; }
        *(bf16x8*)&WF[(((size_t)nt * 32 + kt) * 64 + lane) * 8] = f;
      }
    }
  }
  __syncthreads();

  float cst[4] = {0.f, 0.f, 0.f, 0.f};

  f32x4 gp[2];
  #pragma unroll
  for (int nt = 0; nt < 2; ++nt) {
    size_t idx = (size_t)wrowA[nt] * 64 + bb;
    if (GF32) gp[nt] = *(const f32x4*)((const float*)gates + idx);
    else {
      bf16x4 q = *(const bf16x4*)((const __bf16*)gates + idx);
      #pragma unroll
      for (int j = 0; j < 4; ++j) gp[nt][j] = (float)q[j];
    }
  }

  for (int t = 0; t < 512; ++t) {
    const __bf16* hprev = (t & 1) ? hB : hA;
    __bf16* hnext = (t & 1) ? hA : hB;

    f32x4 acc0 = gp[0], acc1 = gp[1];

    // prefetch next step's gates (normal cached loads; private per block)
    if (t < 511) {
      #pragma unroll
      for (int nt = 0; nt < 2; ++nt) {
        size_t idx = ((size_t)(t + 1) * 4096 + (size_t)wrowA[nt]) * 64 + bb;
        if (GF32) gp[nt] = *(const f32x4*)((const float*)gates + idx);
        else {
          bf16x4 q = *(const bf16x4*)((const __bf16*)gates + idx);
          #pragma unroll
          for (int j = 0; j < 4; ++j) gp[nt][j] = (float)q[j];
        }
      }
    }

    // h @ W_hh^T : A-frags via system-scope (LLC-coherent) u64 loads
    uint64_t* h64 = (uint64_t*)hprev + ((size_t)(bo + cl) << 8) + (rg << 1);
    #pragma unroll
    for (int half = 0; half < 2; ++half) {
      bf16x8 af[16];
      #pragma unroll
      for (int kt = 0; kt < 16; ++kt) {
        uint64_t u0 = __hip_atomic_load(h64 + ((half * 16 + kt) << 3),
                                        __ATOMIC_RELAXED, __HIP_MEMORY_SCOPE_SYSTEM);
        uint64_t u1 = __hip_atomic_load(h64 + ((half * 16 + kt) << 3) + 1,
                                        __ATOMIC_RELAXED, __HIP_MEMORY_SCOPE_SYSTEM);
        union { uint64_t u[2]; bf16x8 v; } cv;
        cv.u[0] = u0; cv.u[1] = u1;
        af[kt] = cv.v;
      }
      #pragma unroll
      for (int kt = 0; kt < 16; ++kt) {
        bf16x8 w0 = *(const bf16x8*)&WF[(((size_t)(half * 16 + kt)) * 64 + lane) * 8];
        bf16x8 w1 = *(const bf16x8*)&WF[(((size_t)(32 + half * 16 + kt)) * 64 + lane) * 8];
        acc0 = mfma16(af[kt], w0, acc0);
        acc1 = mfma16(af[kt], w1, acc1);
      }
    }

    // elementwise: acc0 = {i | f}, acc1 = {g | o}; pair via xor-8
    f32x4 a0s, a1s;
    #pragma unroll
    for (int j = 0; j < 4; ++j) {
      a0s[j] = __shfl_xor(acc0[j], 8, 64);
      a1s[j] = __shfl_xor(acc1[j], 8, 64);
    }
    // all lanes compute (cl>=8 results are garbage, never stored)
    float hv[4], cc[4];
    #pragma unroll
    for (int v = 0; v < 4; ++v) {
      float iv = sigm(acc0[v]);
      float fv = sigm(a0s[v]);
      float gv = tanh_(acc1[v]);
      float ov = sigm(a1s[v]);
      float c = fv * cst[v] + iv * gv;
      cst[v] = c;
      hv[v] = ov * tanh_(c);
      cc[v] = c;
    }
    // pack bf16 pairs across (cl, cl^1) lanes -> u32 system stores to hnext
    #pragma unroll
    for (int v = 0; v < 4; ++v) {
      union { __bf16 b; unsigned short s; } cvt;
      cvt.b = (__bf16)hv[v];
      int me = cvt.s;
      int nb = __shfl_xor(me, 1, 64);
      if (cl < 8 && (cl & 1) == 0) {
        unsigned word = (unsigned)(me & 0xffff) | ((unsigned)(nb & 0xffff) << 16);
        int b = bb + v;
        __hip_atomic_store((unsigned*)hnext + (((size_t)b << 9) + ((hb + cl) >> 1)),
                           word, __ATOMIC_RELAXED, __HIP_MEMORY_SCOPE_SYSTEM);
      }
    }
    if (cl < 8) {
      #pragma unroll
      for (int v = 0; v < 4; ++v) {
        int b = bb + v;
        __builtin_nontemporal_store(hv[v], &out[((size_t)b * 512 + t) * 1024 + hb + cl]);
        if (t == 511) {
          __builtin_nontemporal_store(hv[v], &hlast[(size_t)b * 1024 + hb + cl]);
          __builtin_nontemporal_store(cc[v], &clast[(size_t)b * 1024 + hb + cl]);
        }
      }
    }
    if (t < 511) gridbar(bars, (unsigned)(t + 1) * gridDim.x, blockIdx.x);
  }
}

extern "C" void kernel_launch(void* const* d_in, const int* in_sizes, int n_in,
                              void* d_out, int out_size, void* d_ws, size_t ws_size,
                              hipStream_t stream) {
  const float* x   = (const float*)d_in[0];
  const float* Wih = (const float*)d_in[1];
  const float* bih = (const float*)d_in[2];
  const float* Whh = (const float*)d_in[3];
  const float* bhh = (const float*)d_in[4];
  float* out   = (float*)d_out;
  float* hlast = out + (size_t)64 * 512 * 1024;
  float* clast = hlast + (size_t)64 * 1024;

  char* ws = (char*)d_ws;
  unsigned* bars = (unsigned*)ws;                 // 8 counters, 128B apart
  __bf16* hA = (__bf16*)(ws + 4096);
  __bf16* hB = (__bf16*)(ws + 4096 + 131072);
  void* gates = (void*)(ws + (1 << 20));
  const size_t need_f32 = (size_t)(1 << 20) + (size_t)512 * 4096 * 64 * 4;
  bool gf32 = (ws_size >= need_f32);

  hipMemsetAsync(bars, 0, 1024, stream);
  hipMemsetAsync(hA, 0, 131072, stream);

  if (gf32) {
    k_gates<true><<<8192, 256, 0, stream>>>(x, Wih, bih, bhh, gates);
    k_rnn<true><<<128, 256, 0, stream>>>(gates, Whh, hA, hB, bars, out, hlast, clast);
  } else {
    k_gates<false><<<8192, 256, 0, stream>>>(x, Wih, bih, bhh, gates);
    k_rnn<false><<<128, 256, 0, stream>>>(gates, Whh, hA, hB, bars, out, hlast, clast);
  }
}

// Round 4
// 4854.990 us; speedup vs baseline: 1.4247x; 1.1362x over previous
//
#include <hip/hip_runtime.h>

// LSTM: B=64, T=512, D=512, H=1024, G=4H=4096
// d_out: output[64][512][1024] fp32, then h_last[64][1024], c_last[64][1024]

typedef __attribute__((ext_vector_type(4))) float f32x4;
typedef __attribute__((ext_vector_type(8))) __bf16 bf16x8;
typedef __attribute__((ext_vector_type(4))) __bf16 bf16x4;

__device__ __forceinline__ f32x4 mfma16(bf16x8 a, bf16x8 b, f32x4 c) {
  return __builtin_amdgcn_mfma_f32_16x16x32_bf16(a, b, c, 0, 0, 0);
}
__device__ __forceinline__ float sigm(float x) {
  return __builtin_amdgcn_rcpf(1.0f + __expf(-x));
}
__device__ __forceinline__ float tanh_(float x) {
  return 2.0f * __builtin_amdgcn_rcpf(1.0f + __expf(-2.0f * x)) - 1.0f;
}

// ---------- Phase 1: gates[t][g][b] = sum_d W_ih[g,d]*x[b,t,d] + b_ih[g] + b_hh[g]
template<bool GF32>
__global__ __launch_bounds__(256) void k_gates(
    const float* __restrict__ x, const float* __restrict__ Wih,
    const float* __restrict__ bih, const float* __restrict__ bhh,
    void* __restrict__ gates)
{
  __shared__ __align__(16) __bf16 lA[128][40];
  __shared__ __align__(16) __bf16 lB[128][40];
  int bid = blockIdx.x;
  int grp = bid >> 9;
  int rem = bid & 511;
  int mt = rem & 31;
  int nt = (grp << 4) + (rem >> 5);
  const int m0 = mt << 7, n0 = nt << 7;
  const int tid = threadIdx.x, lane = tid & 63, wave = tid >> 6;
  const int cl = lane & 15, rg = lane >> 4;
  const int wm = (wave >> 1) << 6, wn = (wave & 1) << 6;
  f32x4 acc[4][4] = {};

  const int r = tid >> 1;
  const int kh = (tid & 1) << 4;
  const float* aSrc = Wih + (size_t)(m0 + r) * 512 + kh;
  const int nn = n0 + r;
  const float* bSrc = x + ((size_t)(nn & 63) * 512 + (nn >> 6)) * 512 + kh;

  for (int k0 = 0; k0 < 512; k0 += 32) {
    __syncthreads();
    #pragma unroll
    for (int i = 0; i < 16; i += 4) {
      f32x4 va = *(const f32x4*)(aSrc + k0 + i);
      f32x4 vb = *(const f32x4*)(bSrc + k0 + i);
      bf16x4 pa, pb;
      #pragma unroll
      for (int j = 0; j < 4; ++j) { pa[j] = (__bf16)va[j]; pb[j] = (__bf16)vb[j]; }
      *(bf16x4*)&lA[r][kh + i] = pa;
      *(bf16x4*)&lB[r][kh + i] = pb;
    }
    __syncthreads();
    bf16x8 afr[4], bfr[4];
    #pragma unroll
    for (int q = 0; q < 4; ++q) {
      afr[q] = *(const bf16x8*)&lA[wm + q * 16 + cl][rg * 8];
      bfr[q] = *(const bf16x8*)&lB[wn + q * 16 + cl][rg * 8];
    }
    #pragma unroll
    for (int mi = 0; mi < 4; ++mi)
      #pragma unroll
      for (int ni = 0; ni < 4; ++ni)
        acc[mi][ni] = mfma16(afr[mi], bfr[ni], acc[mi][ni]);
  }

  #pragma unroll
  for (int mi = 0; mi < 4; ++mi) {
    int gb = m0 + wm + mi * 16 + rg * 4;
    f32x4 bsum = *(const f32x4*)(bih + gb);
    bsum += *(const f32x4*)(bhh + gb);
    #pragma unroll
    for (int ni = 0; ni < 4; ++ni) {
      int n = n0 + wn + ni * 16 + cl;
      int tt = n >> 6, bb = n & 63;
      #pragma unroll
      for (int v = 0; v < 4; ++v) {
        float val = acc[mi][ni][v] + bsum[v];
        size_t idx = ((size_t)tt * 4096 + (size_t)(gb + v)) * 64 + bb;
        if (GF32) ((float*)gates)[idx] = val;
        else      ((__bf16*)gates)[idx] = (__bf16)val;
      }
    }
  }
}

// ---------- grid barrier + one agent-acquire (buffer_inv) per block per step.
// h stores are system-scope write-through (reach LLC); __syncthreads drains
// vmcnt before the arrival add. After the poll, wave 0 issues ONE acquire
// fence (invalidates this CU's L1 + this XCD's L2) so the next step's plain
// cached h loads observe fresh data; the trailing __syncthreads orders the
// other waves' loads behind it.
__device__ __forceinline__ void gridbar(unsigned* bars, unsigned target, int bid) {
  __syncthreads();
  if (threadIdx.x < 8) {
    if (threadIdx.x == 0)
      __hip_atomic_fetch_add(&bars[(bid & 7) * 32], 1u, __ATOMIC_RELAXED,
                             __HIP_MEMORY_SCOPE_SYSTEM);
    for (;;) {
      unsigned v = __hip_atomic_load(&bars[threadIdx.x * 32], __ATOMIC_RELAXED,
                                     __HIP_MEMORY_SCOPE_SYSTEM);
      v += __shfl_xor((int)v, 1, 64);
      v += __shfl_xor((int)v, 2, 64);
      v += __shfl_xor((int)v, 4, 64);
      if (v >= target) break;
      __builtin_amdgcn_s_sleep(1);
    }
    __builtin_amdgcn_fence(__ATOMIC_ACQUIRE, "agent");
  }
  __syncthreads();
}

// ---------- Phase 2: persistent recurrence. 128 blocks x 256 thr (4 waves).
// W_hh slice in LDS as B-fragments; h read via PLAIN cached dwordx4 loads
// (L2-resident after per-step invalidate); h written via system-scope stores.
template<bool GF32>
__global__ __launch_bounds__(256, 1) void k_rnn(
    const void* __restrict__ gates, const float* __restrict__ Whh,
    __bf16* __restrict__ hA, __bf16* __restrict__ hB,
    unsigned* __restrict__ bars,
    float* __restrict__ out, float* __restrict__ hlast, float* __restrict__ clast)
{
  __shared__ __align__(16) __bf16 WF[2 * 32 * 64 * 8];  // 64 KB
  const int tid = threadIdx.x, lane = tid & 63, wave = tid >> 6;
  const int cl = lane & 15, rg = lane >> 4;
  const int hb = blockIdx.x << 3;   // 8 hidden units
  const int bo = wave << 4;         // batch offset
  const int bb = bo + rg * 4;       // base batch for acc rows

  int wrowA[2];
  #pragma unroll
  for (int nt = 0; nt < 2; ++nt) {
    int nl = nt * 16 + cl;
    wrowA[nt] = (nl >> 3) * 1024 + hb + (nl & 7);
  }

  if (wave == 0) {
    #pragma unroll
    for (int nt = 0; nt < 2; ++nt) {
      const float* wsrc = Whh + (size_t)wrowA[nt] * 1024 + rg * 8;
      for (int kt = 0; kt < 32; ++kt) {
        f32x4 lo = *(const f32x4*)(wsrc + kt * 32);
        f32x4 hi = *(const f32x4*)(wsrc + kt * 32 + 4);
        bf16x8 f;
        #pragma unroll
        for (int j = 0; j < 4; ++j) { f[j] = (__bf16)lo[j]; f[4 + j] = (__bf16)hi[j]; }
        *(bf16x8*)&WF[(((size_t)nt * 32 + kt) * 64 + lane) * 8] = f;
      }
    }
  }
  __syncthreads();

  float cst[4] = {0.f, 0.f, 0.f, 0.f};

  f32x4 gp[2];
  #pragma unroll
  for (int nt = 0; nt < 2; ++nt) {
    size_t idx = (size_t)wrowA[nt] * 64 + bb;
    if (GF32) gp[nt] = *(const f32x4*)((const float*)gates + idx);
    else {
      bf16x4 q = *(const bf16x4*)((const __bf16*)gates + idx);
      #pragma unroll
      for (int j = 0; j < 4; ++j) gp[nt][j] = (float)q[j];
    }
  }

  for (int t = 0; t < 512; ++t) {
    const __bf16* hprev = (t & 1) ? hB : hA;
    __bf16* hnext = (t & 1) ? hA : hB;

    f32x4 acc0 = gp[0], acc1 = gp[1];

    // prefetch next step's gates into registers (before the barrier)
    if (t < 511) {
      #pragma unroll
      for (int nt = 0; nt < 2; ++nt) {
        size_t idx = ((size_t)(t + 1) * 4096 + (size_t)wrowA[nt]) * 64 + bb;
        if (GF32) gp[nt] = *(const f32x4*)((const float*)gates + idx);
        else {
          bf16x4 q = *(const bf16x4*)((const __bf16*)gates + idx);
          #pragma unroll
          for (int j = 0; j < 4; ++j) gp[nt][j] = (float)q[j];
        }
      }
    }

    // h @ W_hh^T : A-frags via PLAIN cached 16B loads (fresh post-invalidate)
    const __bf16* hrow = hprev + (size_t)(bo + cl) * 1024 + rg * 8;
    #pragma unroll
    for (int half = 0; half < 2; ++half) {
      bf16x8 af[16];
      #pragma unroll
      for (int kt = 0; kt < 16; ++kt)
        af[kt] = *(const bf16x8*)(hrow + (size_t)(half * 16 + kt) * 32);
      #pragma unroll
      for (int kt = 0; kt < 16; ++kt) {
        bf16x8 w0 = *(const bf16x8*)&WF[(((size_t)(half * 16 + kt)) * 64 + lane) * 8];
        bf16x8 w1 = *(const bf16x8*)&WF[(((size_t)(32 + half * 16 + kt)) * 64 + lane) * 8];
        acc0 = mfma16(af[kt], w0, acc0);
        acc1 = mfma16(af[kt], w1, acc1);
      }
    }

    // elementwise: acc0 = {i | f}, acc1 = {g | o}; pair via xor-8
    f32x4 a0s, a1s;
    #pragma unroll
    for (int j = 0; j < 4; ++j) {
      a0s[j] = __shfl_xor(acc0[j], 8, 64);
      a1s[j] = __shfl_xor(acc1[j], 8, 64);
    }
    float hv[4], cc[4];
    #pragma unroll
    for (int v = 0; v < 4; ++v) {
      float iv = sigm(acc0[v]);
      float fv = sigm(a0s[v]);
      float gv = tanh_(acc1[v]);
      float ov = sigm(a1s[v]);
      float c = fv * cst[v] + iv * gv;
      cst[v] = c;
      hv[v] = ov * tanh_(c);
      cc[v] = c;
    }
    // pack bf16 pairs across (cl, cl^1) lanes -> u32 system stores to hnext
    #pragma unroll
    for (int v = 0; v < 4; ++v) {
      union { __bf16 b; unsigned short s; } cvt;
      cvt.b = (__bf16)hv[v];
      int me = cvt.s;
      int nb = __shfl_xor(me, 1, 64);
      if (cl < 8 && (cl & 1) == 0) {
        unsigned word = (unsigned)(me & 0xffff) | ((unsigned)(nb & 0xffff) << 16);
        int b = bb + v;
        __hip_atomic_store((unsigned*)hnext + (((size_t)b << 9) + ((hb + cl) >> 1)),
                           word, __ATOMIC_RELAXED, __HIP_MEMORY_SCOPE_SYSTEM);
      }
    }
    if (cl < 8) {
      #pragma unroll
      for (int v = 0; v < 4; ++v) {
        int b = bb + v;
        __builtin_nontemporal_store(hv[v], &out[((size_t)b * 512 + t) * 1024 + hb + cl]);
        if (t == 511) {
          __builtin_nontemporal_store(hv[v], &hlast[(size_t)b * 1024 + hb + cl]);
          __builtin_nontemporal_store(cc[v], &clast[(size_t)b * 1024 + hb + cl]);
        }
      }
    }
    if (t < 511) gridbar(bars, (unsigned)(t + 1) * gridDim.x, blockIdx.x);
  }
}

extern "C" void kernel_launch(void* const* d_in, const int* in_sizes, int n_in,
                              void* d_out, int out_size, void* d_ws, size_t ws_size,
                              hipStream_t stream) {
  const float* x   = (const float*)d_in[0];
  const float* Wih = (const float*)d_in[1];
  const float* bih = (const float*)d_in[2];
  const float* Whh = (const float*)d_in[3];
  const float* bhh = (const float*)d_in[4];
  float* out   = (float*)d_out;
  float* hlast = out + (size_t)64 * 512 * 1024;
  float* clast = hlast + (size_t)64 * 1024;

  char* ws = (char*)d_ws;
  unsigned* bars = (unsigned*)ws;                 // 8 counters, 128B apart
  __bf16* hA = (__bf16*)(ws + 4096);
  __bf16* hB = (__bf16*)(ws + 4096 + 131072);
  void* gates = (void*)(ws + (1 << 20));
  const size_t need_f32 = (size_t)(1 << 20) + (size_t)512 * 4096 * 64 * 4;
  bool gf32 = (ws_size >= need_f32);

  hipMemsetAsync(bars, 0, 1024, stream);
  hipMemsetAsync(hA, 0, 131072, stream);

  if (gf32) {
    k_gates<true><<<8192, 256, 0, stream>>>(x, Wih, bih, bhh, gates);
    k_rnn<true><<<128, 256, 0, stream>>>(gates, Whh, hA, hB, bars, out, hlast, clast);
  } else {
    k_gates<false><<<8192, 256, 0, stream>>>(x, Wih, bih, bhh, gates);
    k_rnn<false><<<128, 256, 0, stream>>>(gates, Whh, hA, hB, bars, out, hlast, clast);
  }
}